// Round 2
// baseline (1007.553 us; speedup 1.0000x reference)
//
#include <hip/hip_runtime.h>
#include <math.h>

#define BS 1024
#define AA 3072
#define DD 2048
#define NBLK 768            // 3 blocks/CU x 256 CU -> all co-resident (see __launch_bounds__)
#define NTHR 256
#define NWAVES (NBLK * (NTHR / 64))   // 3072 waves, one per output row

__device__ __forceinline__ float wave_reduce(float s) {
#pragma unroll
    for (int off = 32; off; off >>= 1) s += __shfl_down(s, off);
    return s;
}

// Load one W row fragment (N4 float4 per lane, coalesced) into registers.
template<int N4>
__device__ __forceinline__ void load_row(float4* f, const float* __restrict__ W,
                                         int row, int in_dim, int lane) {
    const float4* p = (const float4*)(W + (size_t)row * in_dim);
#pragma unroll
    for (int i = 0; i < N4; ++i) f[i] = p[lane + i * 64];
}

// dot(frag, x) per lane; x loads are L2/MALL-hot (<=12 KB vector).
template<int N4>
__device__ __forceinline__ float dot_row(const float4* f, const float* __restrict__ xp, int lane) {
    const float4* xv = (const float4*)xp;
    float s = 0.f;
#pragma unroll
    for (int i = 0; i < N4; ++i) {
        float4 x4 = xv[lane + i * 64];
        s += f[i].x * x4.x + f[i].y * x4.y + f[i].z * x4.z + f[i].w * x4.w;
    }
    return s;
}

// Device-scope grid barrier: monotone arrival counter, target = phase*NBLK.
// Requires all NBLK blocks co-resident (guaranteed by grid=768 + launch_bounds(256,3)).
// Bounded spin = safety valve: fails loud (bad absmax) instead of hanging.
__device__ __forceinline__ void grid_bar(unsigned* cnt, unsigned target) {
    __syncthreads();                       // all block stores drained (vmcnt(0) before s_barrier)
    if (threadIdx.x == 0) {
        __threadfence();                   // agent-scope release: flush L1/L2 to coherence point
        __hip_atomic_fetch_add(cnt, 1u, __ATOMIC_RELEASE, __HIP_MEMORY_SCOPE_AGENT);
        int guard = 0;
        while (__hip_atomic_load(cnt, __ATOMIC_ACQUIRE, __HIP_MEMORY_SCOPE_AGENT) < target) {
            __builtin_amdgcn_s_sleep(8);   // ~0.2us poll interval, keeps MALL line cool
            if (++guard > 4000000) break;  // ~1s valve
        }
    }
    __syncthreads();                       // other waves' reads now hit invalidated caches
}

__global__ __launch_bounds__(NTHR, 3) void fused_ae(
    const float* __restrict__ x,
    const float* __restrict__ ew1, const float* __restrict__ eb1,
    const float* __restrict__ ew2, const float* __restrict__ eb2,
    const float* __restrict__ ew3, const float* __restrict__ eb3,
    const float* __restrict__ ew4, const float* __restrict__ eb4,
    const float* __restrict__ dw1, const float* __restrict__ db1,
    const float* __restrict__ dw2, const float* __restrict__ db2,
    const float* __restrict__ dw3, const float* __restrict__ db3,
    const float* __restrict__ dw4, const float* __restrict__ db4,
    float* __restrict__ out_y, float* __restrict__ out_ind,
    float* __restrict__ out_lat, float* __restrict__ out_rep,
    float* __restrict__ h1, float* __restrict__ h2, float* __restrict__ h3,
    float* __restrict__ yy, float* __restrict__ g1, float* __restrict__ g2,
    float* __restrict__ g3, unsigned* __restrict__ bar)
{
    const int wave = blockIdx.x * (NTHR / 64) + (int)(threadIdx.x >> 6);
    const int lane = (int)(threadIdx.x & 63);

    float4 A[12], B[12];   // double-buffered W-row fragments (~96 VGPRs)

    // Pre-load e1 row.
    load_row<12>(A, ew1, wave, AA, lane);

    // ---- phase 1: h1 = tanh(e1 . x + eb1); prefetch e2 ----
    {
        float s = dot_row<12>(A, x, lane);
        __builtin_amdgcn_sched_barrier(0);
        load_row<12>(B, ew2, wave, AA, lane);      // streams during reduce+store+barrier
        __builtin_amdgcn_sched_barrier(0);
        s = wave_reduce(s);
        if (lane == 0) h1[wave] = tanhf(s + eb1[wave]);
    }
    grid_bar(bar, 1 * NBLK);

    // ---- phase 2: h2 = tanh(e2 . h1 + eb2); prefetch e3 ----
    {
        float s = dot_row<12>(B, h1, lane);
        __builtin_amdgcn_sched_barrier(0);
        load_row<12>(A, ew3, wave, AA, lane);
        __builtin_amdgcn_sched_barrier(0);
        s = wave_reduce(s);
        if (lane == 0) h2[wave] = tanhf(s + eb2[wave]);
    }
    grid_bar(bar, 2 * NBLK);

    // ---- phase 3: h3 = e3 . h2 + eb3; prefetch e4 (rows < 2048 only) ----
    {
        float s = dot_row<12>(A, h2, lane);
        __builtin_amdgcn_sched_barrier(0);
        if (wave < DD) load_row<12>(B, ew4, wave, AA, lane);
        __builtin_amdgcn_sched_barrier(0);
        s = wave_reduce(s);
        if (lane == 0) h3[wave] = s + eb3[wave];
    }
    grid_bar(bar, 3 * NBLK);

    // ---- phase 4: yy = tanhshrink(e4 . h3 + eb4) (waves<2048); others pdist3(x); prefetch d1 ----
    {
        float s = 0.f;
        if (wave < DD) s = dot_row<12>(B, h3, lane);
        __builtin_amdgcn_sched_barrier(0);
        load_row<8>(A, dw1, wave, DD, lane);       // all waves need a d1 row next phase
        __builtin_amdgcn_sched_barrier(0);
        if (wave < DD) {
            s = wave_reduce(s);
            if (lane == 0) {
                float v = s + eb4[wave];
                v = v - tanhf(v);                  // Tanhshrink
                yy[wave] = v;
                out_rep[wave] = v;
            }
        } else {
            // pdist3 on x -> out_ind, 1M elems over 1024 waves * 64 lanes
            int t = (wave - DD) * 64 + lane;
#pragma unroll
            for (int k = 0; k < 16; ++k) {
                int idx = t + k * 65536;
                int i = idx >> 10, j = idx & 1023;
                float d0 = x[3 * i + 0] - x[3 * j + 0];
                float d1 = x[3 * i + 1] - x[3 * j + 1];
                float d2 = x[3 * i + 2] - x[3 * j + 2];
                out_ind[idx] = sqrtf(d0 * d0 + d1 * d1 + d2 * d2);
            }
        }
    }
    grid_bar(bar, 4 * NBLK);

    // ---- phase 5: g1 = tanh(d1 . yy + db1); pdist2(yy); prefetch d2 ----
    {
        float s = dot_row<8>(A, yy, lane);
        __builtin_amdgcn_sched_barrier(0);
        load_row<12>(B, dw2, wave, AA, lane);
        __builtin_amdgcn_sched_barrier(0);
        s = wave_reduce(s);
        if (lane == 0) g1[wave] = tanhf(s + db1[wave]);
        // pdist2 on yy -> out_lat, 1M elems over all 196608 lanes
        int t = wave * 64 + lane;
#pragma unroll
        for (int k = 0; k < 6; ++k) {
            int idx = t + k * (NWAVES * 64);
            if (idx < BS * BS) {
                int i = idx >> 10, j = idx & 1023;
                float d0 = yy[2 * i + 0] - yy[2 * j + 0];
                float d1 = yy[2 * i + 1] - yy[2 * j + 1];
                out_lat[idx] = sqrtf(d0 * d0 + d1 * d1);
            }
        }
    }
    grid_bar(bar, 5 * NBLK);

    // ---- phase 6: g2 = tanh(d2 . g1 + db2); prefetch d3 ----
    {
        float s = dot_row<12>(B, g1, lane);
        __builtin_amdgcn_sched_barrier(0);
        load_row<12>(A, dw3, wave, AA, lane);
        __builtin_amdgcn_sched_barrier(0);
        s = wave_reduce(s);
        if (lane == 0) g2[wave] = tanhf(s + db2[wave]);
    }
    grid_bar(bar, 6 * NBLK);

    // ---- phase 7: g3 = d3 . g2 + db3; prefetch d4 ----
    {
        float s = dot_row<12>(A, g2, lane);
        __builtin_amdgcn_sched_barrier(0);
        load_row<12>(B, dw4, wave, AA, lane);
        __builtin_amdgcn_sched_barrier(0);
        s = wave_reduce(s);
        if (lane == 0) g3[wave] = s + db3[wave];
    }
    grid_bar(bar, 7 * NBLK);

    // ---- phase 8: out = tanh(d4 . g3 + db4) ----
    {
        float s = dot_row<12>(B, g3, lane);
        s = wave_reduce(s);
        if (lane == 0) out_y[wave] = tanhf(s + db4[wave]);
    }
}

extern "C" void kernel_launch(void* const* d_in, const int* in_sizes, int n_in,
                              void* d_out, int out_size, void* d_ws, size_t ws_size,
                              hipStream_t stream)
{
    const float* x   = (const float*)d_in[0];
    const float* ew1 = (const float*)d_in[1];  const float* eb1 = (const float*)d_in[2];
    const float* ew2 = (const float*)d_in[3];  const float* eb2 = (const float*)d_in[4];
    const float* ew3 = (const float*)d_in[5];  const float* eb3 = (const float*)d_in[6];
    const float* ew4 = (const float*)d_in[7];  const float* eb4 = (const float*)d_in[8];
    const float* dw1 = (const float*)d_in[9];  const float* db1 = (const float*)d_in[10];
    const float* dw2 = (const float*)d_in[11]; const float* db2 = (const float*)d_in[12];
    const float* dw3 = (const float*)d_in[13]; const float* db3 = (const float*)d_in[14];
    const float* dw4 = (const float*)d_in[15]; const float* db4 = (const float*)d_in[16];

    float* out     = (float*)d_out;
    float* out_y   = out;                    // output        [3072]
    float* out_ind = out + AA;               // in_diff_sum   [1024*1024]
    float* out_lat = out_ind + BS * BS;      // lat_diff_sum  [1024*1024]
    float* out_rep = out_lat + BS * BS;      // lat_repr      [2048]

    unsigned* bar = (unsigned*)d_ws;                         // barrier counter @ ws[0]
    float* act = (float*)((char*)d_ws + 256);                // activations after pad
    float* h1 = act;           // [3072]
    float* h2 = h1 + AA;       // [3072]
    float* h3 = h2 + AA;       // [3072]
    float* yy = h3 + AA;       // [2048]
    float* g1 = yy + DD;       // [3072]
    float* g2 = g1 + AA;       // [3072]
    float* g3 = g2 + AA;       // [3072]

    hipMemsetAsync(d_ws, 0, 256, stream);    // zero the barrier counter (ws is poisoned 0xAA)

    fused_ae<<<NBLK, NTHR, 0, stream>>>(
        x, ew1, eb1, ew2, eb2, ew3, eb3, ew4, eb4,
        dw1, db1, dw2, db2, dw3, db3, dw4, db4,
        out_y, out_ind, out_lat, out_rep,
        h1, h2, h3, yy, g1, g2, g3, bar);
}

// Round 3
// 493.773 us; speedup vs baseline: 2.0405x; 2.0405x over previous
//
#include <hip/hip_runtime.h>
#include <math.h>

#define BS 1024
#define AA 3072
#define DD 2048
#define NBLK 768            // 3 blocks/CU x 256 CU -> all co-resident (launch_bounds(256,3))
#define NTHR 256
#define NWAVES (NBLK * (NTHR / 64))   // 3072 waves, one per output row

__device__ __forceinline__ float wave_reduce(float s) {
#pragma unroll
    for (int off = 32; off; off >>= 1) s += __shfl_down(s, off);
    return s;
}

template<int N4>
__device__ __forceinline__ void load_row(float4* f, const float* __restrict__ W,
                                         int row, int in_dim, int lane) {
    const float4* p = (const float4*)(W + (size_t)row * in_dim);
#pragma unroll
    for (int i = 0; i < N4; ++i) f[i] = p[lane + i * 64];
}

template<int N4>
__device__ __forceinline__ float dot_row(const float4* f, const float* xp, int lane) {
    const float4* xv = (const float4*)xp;
    float s = 0.f;
#pragma unroll
    for (int i = 0; i < N4; ++i) {
        float4 x4 = xv[lane + i * 64];
        s += f[i].x * x4.x + f[i].y * x4.y + f[i].z * x4.z + f[i].w * x4.w;
    }
    return s;
}

// Publish one activation value through the coherence point (MALL): relaxed
// agent-scope atomic store = write-through, NO L2 writeback/invalidate.
__device__ __forceinline__ void publish(float* p, float v) {
    __hip_atomic_store(p, v, __ATOMIC_RELAXED, __HIP_MEMORY_SCOPE_AGENT);
}

// Grid barrier with ZERO cache-maintenance ops. __syncthreads() emits
// s_waitcnt vmcnt(0) before s_barrier, so all prior atomic stores have been
// ack'd at MALL before the arrival add. Spin = relaxed agent loads (sc1,
// straight from MALL, no invalidates) at ~0.8us intervals. Consumers' plain
// loads after the barrier miss L2 (lines never cached: producers bypassed L2)
// and fetch the correct MALL data. Bounded spin fails loud, never hangs.
__device__ __forceinline__ void grid_bar(unsigned* cnt, unsigned target) {
    __syncthreads();
    if (threadIdx.x == 0) {
        __hip_atomic_fetch_add(cnt, 1u, __ATOMIC_RELAXED, __HIP_MEMORY_SCOPE_AGENT);
        int guard = 0;
        while (__hip_atomic_load(cnt, __ATOMIC_RELAXED, __HIP_MEMORY_SCOPE_AGENT) < target) {
            __builtin_amdgcn_s_sleep(32);     // ~2048 cyc ~0.85us poll interval
            if (++guard > 250000) break;      // ~0.2s valve
        }
    }
    __syncthreads();
}

__global__ __launch_bounds__(NTHR, 3) void fused_ae(
    const float* __restrict__ x,
    const float* __restrict__ ew1, const float* __restrict__ eb1,
    const float* __restrict__ ew2, const float* __restrict__ eb2,
    const float* __restrict__ ew3, const float* __restrict__ eb3,
    const float* __restrict__ ew4, const float* __restrict__ eb4,
    const float* __restrict__ dw1, const float* __restrict__ db1,
    const float* __restrict__ dw2, const float* __restrict__ db2,
    const float* __restrict__ dw3, const float* __restrict__ db3,
    const float* __restrict__ dw4, const float* __restrict__ db4,
    float* __restrict__ out_y, float* __restrict__ out_ind,
    float* __restrict__ out_lat, float* __restrict__ out_rep,
    float* h1, float* h2, float* h3, float* yy,
    float* g1, float* g2, float* g3, unsigned* bar)
{
    const int wave = blockIdx.x * (NTHR / 64) + (int)(threadIdx.x >> 6);
    const int lane = (int)(threadIdx.x & 63);

    float4 A[12], B[12];   // double-buffered W-row fragments

    load_row<12>(A, ew1, wave, AA, lane);    // pre-load e1 row ASAP

    // ---- phase 1: h1 = tanh(e1 . x + eb1); prefetch e2 ----
    {
        float s = dot_row<12>(A, x, lane);
        __builtin_amdgcn_sched_barrier(0);
        load_row<12>(B, ew2, wave, AA, lane);
        __builtin_amdgcn_sched_barrier(0);
        s = wave_reduce(s);
        if (lane == 0) publish(&h1[wave], tanhf(s + eb1[wave]));
    }
    grid_bar(bar, 1 * NBLK);

    // ---- phase 2: h2 = tanh(e2 . h1 + eb2); prefetch e3 ----
    {
        float s = dot_row<12>(B, h1, lane);
        __builtin_amdgcn_sched_barrier(0);
        load_row<12>(A, ew3, wave, AA, lane);
        __builtin_amdgcn_sched_barrier(0);
        s = wave_reduce(s);
        if (lane == 0) publish(&h2[wave], tanhf(s + eb2[wave]));
    }
    grid_bar(bar, 2 * NBLK);

    // ---- phase 3: h3 = e3 . h2 + eb3; prefetch e4 (rows < 2048) ----
    {
        float s = dot_row<12>(A, h2, lane);
        __builtin_amdgcn_sched_barrier(0);
        if (wave < DD) load_row<12>(B, ew4, wave, AA, lane);
        __builtin_amdgcn_sched_barrier(0);
        s = wave_reduce(s);
        if (lane == 0) publish(&h3[wave], s + eb3[wave]);
    }
    grid_bar(bar, 3 * NBLK);

    // ---- phase 4: yy = tanhshrink(e4 . h3) (waves<2048); others pdist3(x); prefetch d1 ----
    {
        float s = 0.f;
        if (wave < DD) s = dot_row<12>(B, h3, lane);
        __builtin_amdgcn_sched_barrier(0);
        load_row<8>(A, dw1, wave, DD, lane);
        __builtin_amdgcn_sched_barrier(0);
        if (wave < DD) {
            s = wave_reduce(s);
            if (lane == 0) {
                float v = s + eb4[wave];
                v = v - tanhf(v);                  // Tanhshrink
                publish(&yy[wave], v);
                out_rep[wave] = v;                 // plain store: kernel-end release flushes
            }
        } else {
            int t = (wave - DD) * 64 + lane;
#pragma unroll
            for (int k = 0; k < 16; ++k) {
                int idx = t + k * 65536;
                int i = idx >> 10, j = idx & 1023;
                float d0 = x[3 * i + 0] - x[3 * j + 0];
                float d1 = x[3 * i + 1] - x[3 * j + 1];
                float d2 = x[3 * i + 2] - x[3 * j + 2];
                out_ind[idx] = sqrtf(d0 * d0 + d1 * d1 + d2 * d2);
            }
        }
    }
    grid_bar(bar, 4 * NBLK);

    // ---- phase 5: g1 = tanh(d1 . yy + db1); pdist2(yy); prefetch d2 ----
    {
        float s = dot_row<8>(A, yy, lane);
        __builtin_amdgcn_sched_barrier(0);
        load_row<12>(B, dw2, wave, AA, lane);
        __builtin_amdgcn_sched_barrier(0);
        s = wave_reduce(s);
        if (lane == 0) publish(&g1[wave], tanhf(s + db1[wave]));
        int t = wave * 64 + lane;
#pragma unroll
        for (int k = 0; k < 6; ++k) {
            int idx = t + k * (NWAVES * 64);
            if (idx < BS * BS) {
                int i = idx >> 10, j = idx & 1023;
                float d0 = yy[2 * i + 0] - yy[2 * j + 0];
                float d1 = yy[2 * i + 1] - yy[2 * j + 1];
                out_lat[idx] = sqrtf(d0 * d0 + d1 * d1);
            }
        }
    }
    grid_bar(bar, 5 * NBLK);

    // ---- phase 6: g2 = tanh(d2 . g1 + db2); prefetch d3 ----
    {
        float s = dot_row<12>(B, g1, lane);
        __builtin_amdgcn_sched_barrier(0);
        load_row<12>(A, dw3, wave, AA, lane);
        __builtin_amdgcn_sched_barrier(0);
        s = wave_reduce(s);
        if (lane == 0) publish(&g2[wave], tanhf(s + db2[wave]));
    }
    grid_bar(bar, 6 * NBLK);

    // ---- phase 7: g3 = d3 . g2 + db3; prefetch d4 ----
    {
        float s = dot_row<12>(A, g2, lane);
        __builtin_amdgcn_sched_barrier(0);
        load_row<12>(B, dw4, wave, AA, lane);
        __builtin_amdgcn_sched_barrier(0);
        s = wave_reduce(s);
        if (lane == 0) publish(&g3[wave], s + db3[wave]);
    }
    grid_bar(bar, 7 * NBLK);

    // ---- phase 8: out = tanh(d4 . g3 + db4) ----
    {
        float s = dot_row<12>(B, g3, lane);
        s = wave_reduce(s);
        if (lane == 0) out_y[wave] = tanhf(s + db4[wave]);
    }
}

extern "C" void kernel_launch(void* const* d_in, const int* in_sizes, int n_in,
                              void* d_out, int out_size, void* d_ws, size_t ws_size,
                              hipStream_t stream)
{
    const float* x   = (const float*)d_in[0];
    const float* ew1 = (const float*)d_in[1];  const float* eb1 = (const float*)d_in[2];
    const float* ew2 = (const float*)d_in[3];  const float* eb2 = (const float*)d_in[4];
    const float* ew3 = (const float*)d_in[5];  const float* eb3 = (const float*)d_in[6];
    const float* ew4 = (const float*)d_in[7];  const float* eb4 = (const float*)d_in[8];
    const float* dw1 = (const float*)d_in[9];  const float* db1 = (const float*)d_in[10];
    const float* dw2 = (const float*)d_in[11]; const float* db2 = (const float*)d_in[12];
    const float* dw3 = (const float*)d_in[13]; const float* db3 = (const float*)d_in[14];
    const float* dw4 = (const float*)d_in[15]; const float* db4 = (const float*)d_in[16];

    float* out     = (float*)d_out;
    float* out_y   = out;                    // output        [3072]
    float* out_ind = out + AA;               // in_diff_sum   [1024*1024]
    float* out_lat = out_ind + BS * BS;      // lat_diff_sum  [1024*1024]
    float* out_rep = out_lat + BS * BS;      // lat_repr      [2048]

    unsigned* bar = (unsigned*)d_ws;                 // barrier counter @ ws[0]
    float* act = (float*)((char*)d_ws + 256);
    float* h1 = act;           // [3072]
    float* h2 = h1 + AA;       // [3072]
    float* h3 = h2 + AA;       // [3072]
    float* yy = h3 + AA;       // [2048]
    float* g1 = yy + DD;       // [3072]
    float* g2 = g1 + AA;       // [3072]
    float* g3 = g2 + AA;       // [3072]

    hipMemsetAsync(d_ws, 0, 256, stream);    // zero barrier counter (ws poisoned 0xAA)

    fused_ae<<<NBLK, NTHR, 0, stream>>>(
        x, ew1, eb1, ew2, eb2, ew3, eb3, ew4, eb4,
        dw1, db1, dw2, db2, dw3, db3, dw4, db4,
        out_y, out_ind, out_lat, out_rep,
        h1, h2, h3, yy, g1, g2, g3, bar);
}

// Round 4
// 294.266 us; speedup vs baseline: 3.4239x; 1.6780x over previous
//
#include <hip/hip_runtime.h>
#include <math.h>

#define BS 1024
#define AA 3072
#define DD 2048
#define NBLK 768            // 3 blocks/CU x 256 CU -> all co-resident (launch_bounds(256,3))
#define NTHR 256
#define NWAVES (NBLK * (NTHR / 64))   // 3072 waves, one per output row

// ws layout: arrive[768] @ 0 (packed, master sweeps), release @ 8192 (stride
// 16 dwords = 64B -> each poller spins on its own line), activations @ 65536.
#define REL_STRIDE 16

__device__ __forceinline__ float wave_reduce(float s) {
#pragma unroll
    for (int off = 32; off; off >>= 1) s += __shfl_down(s, off);
    return s;
}

template<int N4>
__device__ __forceinline__ void load_row(float4* f, const float* __restrict__ W,
                                         int row, int in_dim, int lane) {
    const float4* p = (const float4*)(W + (size_t)row * in_dim);
#pragma unroll
    for (int i = 0; i < N4; ++i) f[i] = p[lane + i * 64];
}

template<int N4>
__device__ __forceinline__ float dot_row(const float4* f, const float* xp, int lane) {
    const float4* xv = (const float4*)xp;
    float s = 0.f;
#pragma unroll
    for (int i = 0; i < N4; ++i) {
        float4 x4 = xv[lane + i * 64];
        s += f[i].x * x4.x + f[i].y * x4.y + f[i].z * x4.z + f[i].w * x4.w;
    }
    return s;
}

// Publish through MALL: relaxed agent-scope atomic store (write-through,
// no L2 writeback/invalidate anywhere in this kernel).
__device__ __forceinline__ void publish(float* p, float v) {
    __hip_atomic_store(p, v, __ATOMIC_RELAXED, __HIP_MEMORY_SCOPE_AGENT);
}
__device__ __forceinline__ void sigput(unsigned* p, unsigned v) {
    __hip_atomic_store(p, v, __ATOMIC_RELAXED, __HIP_MEMORY_SCOPE_AGENT);
}
__device__ __forceinline__ unsigned sigget(unsigned* p) {
    return __hip_atomic_load(p, __ATOMIC_RELAXED, __HIP_MEMORY_SCOPE_AGENT);
}

// Part 1: drain this block's publishes (s_waitcnt vmcnt(0) inside barrier).
__device__ __forceinline__ void bar_begin() { __syncthreads(); }

// Part 2 (call AFTER issuing next-phase prefetch loads): arrival store,
// master (block 0 wave 0) sweeps packed arrive[] with 12 coalesced wave-wide
// loads, then releases via per-block lines. Pollers spin on their OWN line,
// so no MALL slice sees more than ~a few polls per RTT. First poll's vmcnt
// drain overlaps the prefetch stream with the barrier wait (by design).
__device__ __forceinline__ void bar_end(unsigned phase, unsigned* arrive, unsigned* release) {
    const int tid = (int)threadIdx.x;
    const int bid = (int)blockIdx.x;
    if (tid == 0) sigput(&arrive[bid], phase);

    if (bid == 0) {
        if (tid < 64) {   // master wave: sole poller of arrivals
            int guard = 0;
            for (;;) {
                int ok = 1;
#pragma unroll
                for (int k = 0; k < 12; ++k)
                    ok &= (sigget(&arrive[tid + k * 64]) == phase);
                if (__all(ok)) break;
                __builtin_amdgcn_s_sleep(1);
                if (++guard > 2000000) break;   // fail-loud valve
            }
#pragma unroll
            for (int k = 0; k < 12; ++k)        // release: 64B-strided lines
                sigput(&release[(unsigned)(tid + k * 64) * REL_STRIDE], phase);
        }
    } else if (tid == 0) {
        int guard = 0;
        while (sigget(&release[(unsigned)bid * REL_STRIDE]) != phase) {
            __builtin_amdgcn_s_sleep(2);        // ~128 cyc between own-line polls
            if (++guard > 2000000) break;       // fail-loud valve
        }
    }
    __atomic_signal_fence(__ATOMIC_SEQ_CST);    // compiler: no hoisting past the spin
    __syncthreads();
}

__global__ __launch_bounds__(NTHR, 3) void fused_ae(
    const float* __restrict__ x,
    const float* __restrict__ ew1, const float* __restrict__ eb1,
    const float* __restrict__ ew2, const float* __restrict__ eb2,
    const float* __restrict__ ew3, const float* __restrict__ eb3,
    const float* __restrict__ ew4, const float* __restrict__ eb4,
    const float* __restrict__ dw1, const float* __restrict__ db1,
    const float* __restrict__ dw2, const float* __restrict__ db2,
    const float* __restrict__ dw3, const float* __restrict__ db3,
    const float* __restrict__ dw4, const float* __restrict__ db4,
    float* __restrict__ out_y, float* __restrict__ out_ind,
    float* __restrict__ out_lat, float* __restrict__ out_rep,
    float* h1, float* h2, float* h3, float* yy,
    float* g1, float* g2, float* g3,
    unsigned* arrive, unsigned* release)
{
    const int wave = blockIdx.x * (NTHR / 64) + (int)(threadIdx.x >> 6);
    const int lane = (int)(threadIdx.x & 63);

    float4 A[12], B[12];   // double-buffered W-row fragments

    load_row<12>(A, ew1, wave, AA, lane);    // phase-1 rows

    // ---- phase 1: h1 = tanh(e1 . x + eb1) ----
    {
        float s = dot_row<12>(A, x, lane);
        s = wave_reduce(s);
        if (lane == 0) publish(&h1[wave], tanhf(s + eb1[wave]));
    }
    bar_begin();
    load_row<12>(B, ew2, wave, AA, lane);    // prefetch streams through the barrier wait
    bar_end(1, arrive, release);

    // ---- phase 2: h2 = tanh(e2 . h1 + eb2) ----
    {
        float s = dot_row<12>(B, h1, lane);
        s = wave_reduce(s);
        if (lane == 0) publish(&h2[wave], tanhf(s + eb2[wave]));
    }
    bar_begin();
    load_row<12>(A, ew3, wave, AA, lane);
    bar_end(2, arrive, release);

    // ---- phase 3: h3 = e3 . h2 + eb3 ----
    {
        float s = dot_row<12>(A, h2, lane);
        s = wave_reduce(s);
        if (lane == 0) publish(&h3[wave], s + eb3[wave]);
    }
    bar_begin();
    if (wave < DD) load_row<12>(B, ew4, wave, AA, lane);
    bar_end(3, arrive, release);

    // ---- phase 4: yy = tanhshrink(e4 . h3) (waves<2048); others pdist3(x) ----
    {
        if (wave < DD) {
            float s = dot_row<12>(B, h3, lane);
            s = wave_reduce(s);
            if (lane == 0) {
                float v = s + eb4[wave];
                v = v - tanhf(v);                  // Tanhshrink
                publish(&yy[wave], v);
                out_rep[wave] = v;
            }
        } else {
            int t = (wave - DD) * 64 + lane;
#pragma unroll
            for (int k = 0; k < 16; ++k) {
                int idx = t + k * 65536;
                int i = idx >> 10, j = idx & 1023;
                float d0 = x[3 * i + 0] - x[3 * j + 0];
                float d1 = x[3 * i + 1] - x[3 * j + 1];
                float d2 = x[3 * i + 2] - x[3 * j + 2];
                out_ind[idx] = sqrtf(d0 * d0 + d1 * d1 + d2 * d2);
            }
        }
    }
    bar_begin();
    load_row<8>(A, dw1, wave, DD, lane);
    bar_end(4, arrive, release);

    // ---- phase 5: g1 = tanh(d1 . yy + db1); pdist2(yy) ----
    {
        float s = dot_row<8>(A, yy, lane);
        s = wave_reduce(s);
        if (lane == 0) publish(&g1[wave], tanhf(s + db1[wave]));
        int t = wave * 64 + lane;
#pragma unroll
        for (int k = 0; k < 6; ++k) {
            int idx = t + k * (NWAVES * 64);
            if (idx < BS * BS) {
                int i = idx >> 10, j = idx & 1023;
                float d0 = yy[2 * i + 0] - yy[2 * j + 0];
                float d1 = yy[2 * i + 1] - yy[2 * j + 1];
                out_lat[idx] = sqrtf(d0 * d0 + d1 * d1);
            }
        }
    }
    bar_begin();
    load_row<12>(B, dw2, wave, AA, lane);
    bar_end(5, arrive, release);

    // ---- phase 6: g2 = tanh(d2 . g1 + db2) ----
    {
        float s = dot_row<12>(B, g1, lane);
        s = wave_reduce(s);
        if (lane == 0) publish(&g2[wave], tanhf(s + db2[wave]));
    }
    bar_begin();
    load_row<12>(A, dw3, wave, AA, lane);
    bar_end(6, arrive, release);

    // ---- phase 7: g3 = d3 . g2 + db3 ----
    {
        float s = dot_row<12>(A, g2, lane);
        s = wave_reduce(s);
        if (lane == 0) publish(&g3[wave], s + db3[wave]);
    }
    bar_begin();
    load_row<12>(B, dw4, wave, AA, lane);
    bar_end(7, arrive, release);

    // ---- phase 8: out = tanh(d4 . g3 + db4) ----
    {
        float s = dot_row<12>(B, g3, lane);
        s = wave_reduce(s);
        if (lane == 0) out_y[wave] = tanhf(s + db4[wave]);
    }
}

extern "C" void kernel_launch(void* const* d_in, const int* in_sizes, int n_in,
                              void* d_out, int out_size, void* d_ws, size_t ws_size,
                              hipStream_t stream)
{
    const float* x   = (const float*)d_in[0];
    const float* ew1 = (const float*)d_in[1];  const float* eb1 = (const float*)d_in[2];
    const float* ew2 = (const float*)d_in[3];  const float* eb2 = (const float*)d_in[4];
    const float* ew3 = (const float*)d_in[5];  const float* eb3 = (const float*)d_in[6];
    const float* ew4 = (const float*)d_in[7];  const float* eb4 = (const float*)d_in[8];
    const float* dw1 = (const float*)d_in[9];  const float* db1 = (const float*)d_in[10];
    const float* dw2 = (const float*)d_in[11]; const float* db2 = (const float*)d_in[12];
    const float* dw3 = (const float*)d_in[13]; const float* db3 = (const float*)d_in[14];
    const float* dw4 = (const float*)d_in[15]; const float* db4 = (const float*)d_in[16];

    float* out     = (float*)d_out;
    float* out_y   = out;                    // output        [3072]
    float* out_ind = out + AA;               // in_diff_sum   [1024*1024]
    float* out_lat = out_ind + BS * BS;      // lat_diff_sum  [1024*1024]
    float* out_rep = out_lat + BS * BS;      // lat_repr      [2048]

    unsigned* arrive  = (unsigned*)d_ws;                       // [768] packed
    unsigned* release = (unsigned*)((char*)d_ws + 8192);       // [768*16] 64B-strided
    float* act = (float*)((char*)d_ws + 65536);
    float* h1 = act;           // [3072]
    float* h2 = h1 + AA;       // [3072]
    float* h3 = h2 + AA;       // [3072]
    float* yy = h3 + AA;       // [2048]
    float* g1 = yy + DD;       // [3072]
    float* g2 = g1 + AA;       // [3072]
    float* g3 = g2 + AA;       // [3072]

    hipMemsetAsync(d_ws, 0, 65536, stream);  // zero arrive/release (ws poisoned 0xAA)

    fused_ae<<<NBLK, NTHR, 0, stream>>>(
        x, ew1, eb1, ew2, eb2, ew3, eb3, ew4, eb4,
        dw1, db1, dw2, db2, dw3, db3, dw4, db4,
        out_y, out_ind, out_lat, out_rep,
        h1, h2, h3, yy, g1, g2, g3, arrive, release);
}